// Round 5
// baseline (278.662 us; speedup 1.0000x reference)
//
#include <hip/hip_runtime.h>
#include <hip/hip_bf16.h>

#define DIM 256
#define CAP 64
#define GEMM_BX 64

typedef short bf16x8 __attribute__((ext_vector_type(8)));
typedef float f32x4  __attribute__((ext_vector_type(4)));
typedef unsigned int u32x4 __attribute__((ext_vector_type(4)));

__device__ __forceinline__ unsigned short f2b(float f) {
    union { __hip_bfloat16 h; unsigned short u; } cv;
    cv.h = __float2bfloat16(f);
    return cv.u;
}
__device__ __forceinline__ float b2f(unsigned short u) {
    return __uint_as_float(((unsigned)u) << 16);
}
// accumulate 8 bf16 (one u32x4) into a[0..7]
__device__ __forceinline__ void acc8(u32x4 u, float* a) {
    a[0] += __uint_as_float(u.x << 16); a[1] += __uint_as_float(u.x & 0xffff0000u);
    a[2] += __uint_as_float(u.y << 16); a[3] += __uint_as_float(u.y & 0xffff0000u);
    a[4] += __uint_as_float(u.z << 16); a[5] += __uint_as_float(u.z & 0xffff0000u);
    a[6] += __uint_as_float(u.w << 16); a[7] += __uint_as_float(u.w & 0xffff0000u);
}

// ---- ws layout (bytes) ----
#define OFF_FILL   0
#define OFF_WT1    262144
#define OFF_WT2    393216
#define OFF_BUCKET 524288
#define OFF_AGG    6924544ull
#define OFF_YB     32524544ull
#define NEED_BF    (OFF_YB + 25600000ull)

__global__ void k_fill(const int* __restrict__ src, const int* __restrict__ dst,
                       int* __restrict__ fill, unsigned short* __restrict__ bucket, int nE) {
    int e = blockIdx.x * blockDim.x + threadIdx.x;
    if (e < nE) {
        int d = dst[e];
        int pos = atomicAdd(&fill[d], 1);
        if (pos < CAP) bucket[d * CAP + pos] = (unsigned short)src[e];
    }
}

// fused prep: blocks [0, nybBlocks) build yb (8 elems/thread);
// blocks [nybBlocks, +256) transpose-convert W1/W2 to bf16 [n][k].
__global__ void k_prep(const float* __restrict__ x, const int* __restrict__ fill,
                       u32x4* __restrict__ yb,
                       const float* __restrict__ W1, const float* __restrict__ W2,
                       unsigned short* __restrict__ wt1, unsigned short* __restrict__ wt2,
                       int nybBlocks, int n8) {
    if ((int)blockIdx.x < nybBlocks) {
        int t = blockIdx.x * 256 + threadIdx.x;    // 8-elem group index
        if (t < n8) {
            float d = rsqrtf((float)(1 + fill[t >> 5]));   // 32 groups per node
            const f32x4* xp = (const f32x4*)x + t * 2;
            f32x4 v0 = xp[0], v1 = xp[1];
            u32x4 r;
            r.x = (unsigned)f2b(d * v0.x) | ((unsigned)f2b(d * v0.y) << 16);
            r.y = (unsigned)f2b(d * v0.z) | ((unsigned)f2b(d * v0.w) << 16);
            r.z = (unsigned)f2b(d * v1.x) | ((unsigned)f2b(d * v1.y) << 16);
            r.w = (unsigned)f2b(d * v1.z) | ((unsigned)f2b(d * v1.w) << 16);
            yb[t] = r;
        }
    } else {
        int t = (blockIdx.x - nybBlocks) * 256 + threadIdx.x;  // t = n*256 + k
        if (t < DIM * DIM) {
            int k = t & 255, nn = t >> 8;
            wt1[t] = f2b(W1[k * DIM + nn]);
            wt2[t] = f2b(W2[k * DIM + nn]);
        }
    }
}

// v4: XCD-pinned feature-slice aggregation.
// R3 counters (v3): 58us, VALUBusy 25%, request-side 7.5 TB/s (20% of L2),
// FETCH 185MB = 3.2 TB/s L2-miss traffic -> bound by L2-miss/IF-fabric path:
// yb (25.6MB) >> 4MB per-XCD L2, random gathers ~16% hit. Fix: slice D=256
// into 8x 64B column-slices; slice = blockIdx&7 rides the round-robin
// workgroup->XCD dispatch so each XCD gathers from a 3.2MB slice that FITS
// its private L2. Bucket/fill reads replicate x8 but stream (nontemporal).
// 4-lane groups, 1 node/group, 8-wide gather pipeline + masked tail.
__global__ void k_agg_bf(const u32x4* __restrict__ yb, const int* __restrict__ fill,
                         const unsigned short* __restrict__ bucket,
                         u32x4* __restrict__ aggbf, int n) {
    int slice = blockIdx.x & 7;                 // XCD-pinned column-slice
    int nb    = blockIdx.x >> 3;                // node-block (64 nodes)
    int tid   = threadIdx.x;
    int node  = nb * 64 + (tid >> 2);
    int off   = slice * 4 + (tid & 3);          // 16B chunk index within row
    if (node >= n) return;

    float a[8];
    u32x4 s = yb[(size_t)node * 32 + off];
#pragma unroll
    for (int i = 0; i < 8; i++) a[i] = 0.f;
    acc8(s, a);

    int c = __builtin_nontemporal_load(&fill[node]);
    float di = rsqrtf((float)(1 + c));
    if (c > CAP) c = CAP;
    const unsigned short* bk = bucket + (size_t)node * CAP;

    int kfull = c & ~7;
    for (int k = 0; k < kfull; k += 8) {
        u32x4 iv = __builtin_nontemporal_load((const u32x4*)(bk + k)); // 8 u16 idx
        int j0 = iv.x & 0xffff, j1 = iv.x >> 16;
        int j2 = iv.y & 0xffff, j3 = iv.y >> 16;
        int j4 = iv.z & 0xffff, j5 = iv.z >> 16;
        int j6 = iv.w & 0xffff, j7 = iv.w >> 16;
        u32x4 r0 = yb[(size_t)j0 * 32 + off];
        u32x4 r1 = yb[(size_t)j1 * 32 + off];
        u32x4 r2 = yb[(size_t)j2 * 32 + off];
        u32x4 r3 = yb[(size_t)j3 * 32 + off];
        u32x4 r4 = yb[(size_t)j4 * 32 + off];
        u32x4 r5 = yb[(size_t)j5 * 32 + off];
        u32x4 r6 = yb[(size_t)j6 * 32 + off];
        u32x4 r7 = yb[(size_t)j7 * 32 + off];
        acc8(r0, a); acc8(r1, a); acc8(r2, a); acc8(r3, a);
        acc8(r4, a); acc8(r5, a); acc8(r6, a); acc8(r7, a);
    }
    int rem = c - kfull;                        // 0..7
    if (rem) {
        u32x4 iv = __builtin_nontemporal_load((const u32x4*)(bk + kfull));
        int j0 = iv.x & 0xffff, j1 = iv.x >> 16;
        int j2 = iv.y & 0xffff, j3 = iv.y >> 16;
        int j4 = iv.z & 0xffff, j5 = iv.z >> 16;
        int j6 = iv.w & 0xffff;
        j1 = (rem > 1) ? j1 : 0;
        j2 = (rem > 2) ? j2 : 0;
        j3 = (rem > 3) ? j3 : 0;
        j4 = (rem > 4) ? j4 : 0;
        j5 = (rem > 5) ? j5 : 0;
        j6 = (rem > 6) ? j6 : 0;
        u32x4 r0 = yb[(size_t)j0 * 32 + off];
        u32x4 r1 = yb[(size_t)j1 * 32 + off];
        u32x4 r2 = yb[(size_t)j2 * 32 + off];
        u32x4 r3 = yb[(size_t)j3 * 32 + off];
        u32x4 r4 = yb[(size_t)j4 * 32 + off];
        u32x4 r5 = yb[(size_t)j5 * 32 + off];
        u32x4 r6 = yb[(size_t)j6 * 32 + off];
        acc8(r0, a);
        if (rem > 1) acc8(r1, a);
        if (rem > 2) acc8(r2, a);
        if (rem > 3) acc8(r3, a);
        if (rem > 4) acc8(r4, a);
        if (rem > 5) acc8(r5, a);
        if (rem > 6) acc8(r6, a);
    }

    u32x4 r;
    r.x = (unsigned)f2b(a[0] * di) | ((unsigned)f2b(a[1] * di) << 16);
    r.y = (unsigned)f2b(a[2] * di) | ((unsigned)f2b(a[3] * di) << 16);
    r.z = (unsigned)f2b(a[4] * di) | ((unsigned)f2b(a[5] * di) << 16);
    r.w = (unsigned)f2b(a[6] * di) | ((unsigned)f2b(a[7] * di) << 16);
    __builtin_nontemporal_store(r, &aggbf[(size_t)node * 32 + off]);
}

// fp32 fallback (only if ws too small for yb)
__global__ void k_agg_f32(const float4* __restrict__ x4, const int* __restrict__ fill,
                          const unsigned short* __restrict__ bucket,
                          ushort4* __restrict__ aggbf, int n) {
    int node = (blockIdx.x * blockDim.x + threadIdx.x) >> 6;
    int lane = threadIdx.x & 63;
    if (node >= n) return;

    int c = fill[node];
    float di = rsqrtf((float)(1 + c));
    if (c > CAP) c = CAP;

    float4 xi = x4[(size_t)node * 64 + lane];
    float a0 = di * xi.x, a1 = di * xi.y, a2 = di * xi.z, a3 = di * xi.w;

    const unsigned short* bk = bucket + (size_t)node * CAP;
    for (int k = 0; k < c; k++) {
        int j = bk[k];
        float dj = rsqrtf((float)(1 + fill[j]));
        float4 xj = x4[(size_t)j * 64 + lane];
        a0 += dj * xj.x; a1 += dj * xj.y; a2 += dj * xj.z; a3 += dj * xj.w;
    }
    ushort4 r;
    r.x = f2b(a0 * di); r.y = f2b(a1 * di);
    r.z = f2b(a2 * di); r.w = f2b(a3 * di);
    aggbf[(size_t)node * 64 + lane] = r;
}

// GEMM v3: register-resident weight-stationary (R3 win; keep).
// 32-col blocks (grid.y=8); wave = 16 rows x 32 cols; both matrices' weight
// fragments in 128 VGPR (read once from 32KB LDS stage); K-loop pure reg MFMA;
// all 8 A-loads issued up front; swapped mfma(w,a,acc) -> float4 nt stores.
__launch_bounds__(256, 2)
__global__ void k_gemm(const short* __restrict__ aggbf,
                       const short* __restrict__ wt1, const short* __restrict__ wt2,
                       const float* __restrict__ b1, const float* __restrict__ b2,
                       float* __restrict__ out, int n, int ntiles) {
    __shared__ u32x4 bs[2048];   // [mat][nn 0..31][p 0..31] XOR-swizzled, 32 KB

    int c0  = blockIdx.y * 32;
    int tid = threadIdx.x;

#pragma unroll
    for (int i = 0; i < 8; i++) {
        int l = tid + i * 256;                 // 0..2047
        int m = l >> 10, rem = l & 1023, nn = rem >> 5, p = rem & 31;
        const short* base = (m == 0) ? wt1 : wt2;
        const u32x4* sp = (const u32x4*)(base + (size_t)(c0 + nn) * DIM) + p;
        bs[(m << 10) + (nn << 5) + (p ^ nn)] = *sp;
    }
    __syncthreads();

    int lane = tid & 63;
    int wave = tid >> 6;
    int lrow = lane & 15;
    int quad = lane >> 4;

    // one-time: weight fragments -> registers (32 x bf16x8 = 128 VGPR)
    bf16x8 w1r[2][8], w2r[2][8];
#pragma unroll
    for (int ct = 0; ct < 2; ct++) {
        int nn = ct * 16 + lrow;
#pragma unroll
        for (int s = 0; s < 8; s++) {
            int p = (4 * s + quad) ^ nn;
            u32x4 u = bs[(nn << 5) + p];
            u32x4 v = bs[1024 + (nn << 5) + p];
            __builtin_memcpy(&w1r[ct][s], &u, 16);
            __builtin_memcpy(&w2r[ct][s], &v, 16);
        }
    }

    f32x4 bb1[2], bb2[2];
#pragma unroll
    for (int ct = 0; ct < 2; ct++) {
        bb1[ct] = *(const f32x4*)&b1[c0 + ct * 16 + quad * 4];
        bb2[ct] = *(const f32x4*)&b2[c0 + ct * 16 + quad * 4];
    }

    for (int t = blockIdx.x; t < ntiles; t += gridDim.x) {
        int row = t * 64 + wave * 16 + lrow;
        int r = (row < n) ? row : 0;
        const short* ap = aggbf + (size_t)r * DIM + quad * 8;

        // all 8 K-chunks of this row issued together: one latency exposure
        bf16x8 A[8];
#pragma unroll
        for (int s = 0; s < 8; s++) A[s] = *(const bf16x8*)(ap + s * 32);

        f32x4 acc1[2], acc2[2];
#pragma unroll
        for (int ct = 0; ct < 2; ct++) {
            acc1[ct] = (f32x4){0.f, 0.f, 0.f, 0.f};
            acc2[ct] = (f32x4){0.f, 0.f, 0.f, 0.f};
        }

#pragma unroll
        for (int s = 0; s < 8; s++) {
#pragma unroll
            for (int ct = 0; ct < 2; ct++) {
                acc1[ct] = __builtin_amdgcn_mfma_f32_16x16x32_bf16(w1r[ct][s], A[s], acc1[ct], 0, 0, 0);
                acc2[ct] = __builtin_amdgcn_mfma_f32_16x16x32_bf16(w2r[ct][s], A[s], acc2[ct], 0, 0, 0);
            }
        }

        if (row < n) {
#pragma unroll
            for (int ct = 0; ct < 2; ct++) {
                f32x4 v;
#pragma unroll
                for (int i = 0; i < 4; i++)
                    v[i] = fmaxf(acc1[ct][i] + bb1[ct][i], 0.f) + acc2[ct][i] + bb2[ct][i];
                f32x4* dstp = (f32x4*)&out[(size_t)row * DIM + c0 + ct * 16 + quad * 4];
                __builtin_nontemporal_store(v, dstp);
            }
        }
    }
}

extern "C" void kernel_launch(void* const* d_in, const int* in_sizes, int n_in,
                              void* d_out, int out_size, void* d_ws, size_t ws_size,
                              hipStream_t stream) {
    const float* x  = (const float*)d_in[0];
    const int*   ei = (const int*)d_in[1];    // [2, E] row-major, int32
    const float* W1 = (const float*)d_in[2];
    const float* b1 = (const float*)d_in[3];
    const float* W2 = (const float*)d_in[4];
    const float* b2 = (const float*)d_in[5];
    float* out = (float*)d_out;

    int n = in_sizes[0] / DIM;                // 50000
    int E = in_sizes[1] / 2;                  // 800000
    const int* src = ei;
    const int* dst = ei + E;

    char* ws = (char*)d_ws;
    int*            fill   = (int*)(ws + OFF_FILL);
    unsigned short* wt1    = (unsigned short*)(ws + OFF_WT1);
    unsigned short* wt2    = (unsigned short*)(ws + OFF_WT2);
    unsigned short* bucket = (unsigned short*)(ws + OFF_BUCKET);
    char*           aggp   = ws + OFF_AGG;
    u32x4*          yb     = (u32x4*)(ws + OFF_YB);

    (void)hipMemsetAsync(fill, 0, n * sizeof(int), stream);

    k_fill<<<(E + 255) / 256, 256, 0, stream>>>(src, dst, fill, bucket, E);

    bool use_bf = (ws_size >= NEED_BF);      // constant across calls -> graph-safe
    if (use_bf) {
        int n8 = n * (DIM / 8);              // 1.6M 8-elem groups
        int nybBlocks = (n8 + 255) / 256;    // 6250
        k_prep<<<nybBlocks + 256, 256, 0, stream>>>(x, fill, yb, W1, W2, wt1, wt2,
                                                    nybBlocks, n8);
        // 8 slices x 64 nodes/block; slice = blockIdx&7 -> XCD-pinned
        int aggBlocks = ((n + 63) / 64) * 8;  // 782*8 = 6256
        k_agg_bf<<<aggBlocks, 256, 0, stream>>>(yb, fill, bucket, (u32x4*)aggp, n);
    } else {
        k_prep<<<256, 256, 0, stream>>>(x, fill, yb, W1, W2, wt1, wt2, 0, 0);
        int aggBlocks = (n * 64 + 255) / 256;
        k_agg_f32<<<aggBlocks, 256, 0, stream>>>((const float4*)x, fill, bucket,
                                                 (ushort4*)aggp, n);
    }

    int ntiles = (n + 63) / 64;              // 782 row-tiles of 64
    dim3 ggrid(GEMM_BX, DIM / 32);           // 64 x 8 = 512 blocks (2/CU resident)
    k_gemm<<<ggrid, 256, 0, stream>>>((const short*)aggp, (const short*)wt1,
                                      (const short*)wt2, b1, b2, out, n, ntiles);
}

// Round 7
// 257.628 us; speedup vs baseline: 1.0816x; 1.0816x over previous
//
#include <hip/hip_runtime.h>
#include <hip/hip_bf16.h>

#define DIM 256
#define CAP 64
#define GEMM_BX 64

typedef short bf16x8 __attribute__((ext_vector_type(8)));
typedef float f32x4  __attribute__((ext_vector_type(4)));
typedef unsigned int u32x4 __attribute__((ext_vector_type(4)));

__device__ __forceinline__ unsigned short f2b(float f) {
    union { __hip_bfloat16 h; unsigned short u; } cv;
    cv.h = __float2bfloat16(f);
    return cv.u;
}
__device__ __forceinline__ float b2f(unsigned short u) {
    return __uint_as_float(((unsigned)u) << 16);
}
// accumulate 8 bf16 (one u32x4) into a[0..7]
__device__ __forceinline__ void acc8(u32x4 u, float* a) {
    a[0] += __uint_as_float(u.x << 16); a[1] += __uint_as_float(u.x & 0xffff0000u);
    a[2] += __uint_as_float(u.y << 16); a[3] += __uint_as_float(u.y & 0xffff0000u);
    a[4] += __uint_as_float(u.z << 16); a[5] += __uint_as_float(u.z & 0xffff0000u);
    a[6] += __uint_as_float(u.w << 16); a[7] += __uint_as_float(u.w & 0xffff0000u);
}

// ---- ws layout (bytes) ----
#define OFF_FILL   0
#define OFF_WT1    262144
#define OFF_WT2    393216
#define OFF_BUCKET 524288
#define OFF_AGG    6924544ull
#define OFF_YB     32524544ull
#define NEED_BF    (OFF_YB + 25600000ull)

__global__ void k_fill(const int* __restrict__ src, const int* __restrict__ dst,
                       int* __restrict__ fill, unsigned short* __restrict__ bucket, int nE) {
    int e = blockIdx.x * blockDim.x + threadIdx.x;
    if (e < nE) {
        int d = dst[e];
        int pos = atomicAdd(&fill[d], 1);
        if (pos < CAP) bucket[d * CAP + pos] = (unsigned short)src[e];
    }
}

// fused prep: blocks [0, nybBlocks) build yb SLICE-MAJOR (8 elems/thread);
// blocks [nybBlocks, +256) transpose-convert W1/W2 to bf16 [n][k].
// yb layout v6: 8 slice-tables, table s = yb[((s*nN + node)*4 + chunk]
// (u32x4 units): each table 50000x64B = 3.2MB contiguous -> fits 4MB XCD L2
// with NO cache-line sharing between slices (R5 failure mode).
__global__ void k_prep(const float* __restrict__ x, const int* __restrict__ fill,
                       u32x4* __restrict__ yb,
                       const float* __restrict__ W1, const float* __restrict__ W2,
                       unsigned short* __restrict__ wt1, unsigned short* __restrict__ wt2,
                       int nybBlocks, int n8) {
    if ((int)blockIdx.x < nybBlocks) {
        int t = blockIdx.x * 256 + threadIdx.x;    // 8-elem group index
        if (t < n8) {
            int node = t >> 5, g = t & 31;         // g = 16B-chunk idx in row
            int nN = n8 >> 5;                      // node count
            float d = rsqrtf((float)(1 + fill[node]));
            const f32x4* xp = (const f32x4*)x + t * 2;
            f32x4 v0 = xp[0], v1 = xp[1];
            u32x4 r;
            r.x = (unsigned)f2b(d * v0.x) | ((unsigned)f2b(d * v0.y) << 16);
            r.y = (unsigned)f2b(d * v0.z) | ((unsigned)f2b(d * v0.w) << 16);
            r.z = (unsigned)f2b(d * v1.x) | ((unsigned)f2b(d * v1.y) << 16);
            r.w = (unsigned)f2b(d * v1.z) | ((unsigned)f2b(d * v1.w) << 16);
            yb[((size_t)(g >> 2) * nN + node) * 4 + (g & 3)] = r;
        }
    } else {
        int t = (blockIdx.x - nybBlocks) * 256 + threadIdx.x;  // t = n*256 + k
        if (t < DIM * DIM) {
            int k = t & 255, nn = t >> 8;
            wt1[t] = f2b(W1[k * DIM + nn]);
            wt2[t] = f2b(W2[k * DIM + nn]);
        }
    }
}

// v6: XCD-pinned aggregation over SLICE-MAJOR yb.
// R5 post-mortem: row-major 64B slices share 128B lines across slices ->
// per-XCD line working set 6.4MB > 4MB L2, zero locality gain, +44MB bucket
// replication = regression. v6: slice s is a contiguous 3.2MB table; block
// slice = blockIdx&7 rides round-robin workgroup->XCD dispatch -> each XCD
// gathers from an L2-resident table. Decisive test of the %8 pinning theory:
// FETCH ~85MB if true, >=180MB if false (then revert to R3-v3 agg).
__global__ void k_agg_bf(const u32x4* __restrict__ yb, const int* __restrict__ fill,
                         const unsigned short* __restrict__ bucket,
                         u32x4* __restrict__ aggbf, int n) {
    int slice = blockIdx.x & 7;                 // XCD-pinned column-slice
    int nb    = blockIdx.x >> 3;                // node-block (64 nodes)
    int tid   = threadIdx.x;
    int node  = nb * 64 + (tid >> 2);
    int ch    = tid & 3;                        // 16B chunk within 64B slice
    if (node >= n) return;

    const u32x4* ybs = yb + (size_t)slice * n * 4;   // this XCD's 3.2MB table

    float a[8];
    u32x4 s = ybs[(size_t)node * 4 + ch];
#pragma unroll
    for (int i = 0; i < 8; i++) a[i] = 0.f;
    acc8(s, a);

    int c = __builtin_nontemporal_load(&fill[node]);
    float di = rsqrtf((float)(1 + c));
    if (c > CAP) c = CAP;
    const unsigned short* bk = bucket + (size_t)node * CAP;

    int kfull = c & ~7;
    for (int k = 0; k < kfull; k += 8) {
        u32x4 iv = __builtin_nontemporal_load((const u32x4*)(bk + k)); // 8 u16 idx
        int j0 = iv.x & 0xffff, j1 = iv.x >> 16;
        int j2 = iv.y & 0xffff, j3 = iv.y >> 16;
        int j4 = iv.z & 0xffff, j5 = iv.z >> 16;
        int j6 = iv.w & 0xffff, j7 = iv.w >> 16;
        u32x4 r0 = ybs[(size_t)j0 * 4 + ch];
        u32x4 r1 = ybs[(size_t)j1 * 4 + ch];
        u32x4 r2 = ybs[(size_t)j2 * 4 + ch];
        u32x4 r3 = ybs[(size_t)j3 * 4 + ch];
        u32x4 r4 = ybs[(size_t)j4 * 4 + ch];
        u32x4 r5 = ybs[(size_t)j5 * 4 + ch];
        u32x4 r6 = ybs[(size_t)j6 * 4 + ch];
        u32x4 r7 = ybs[(size_t)j7 * 4 + ch];
        acc8(r0, a); acc8(r1, a); acc8(r2, a); acc8(r3, a);
        acc8(r4, a); acc8(r5, a); acc8(r6, a); acc8(r7, a);
    }
    int rem = c - kfull;                        // 0..7
    if (rem) {
        u32x4 iv = __builtin_nontemporal_load((const u32x4*)(bk + kfull));
        int j0 = iv.x & 0xffff, j1 = iv.x >> 16;
        int j2 = iv.y & 0xffff, j3 = iv.y >> 16;
        int j4 = iv.z & 0xffff, j5 = iv.z >> 16;
        int j6 = iv.w & 0xffff;
        j1 = (rem > 1) ? j1 : 0;
        j2 = (rem > 2) ? j2 : 0;
        j3 = (rem > 3) ? j3 : 0;
        j4 = (rem > 4) ? j4 : 0;
        j5 = (rem > 5) ? j5 : 0;
        j6 = (rem > 6) ? j6 : 0;
        u32x4 r0 = ybs[(size_t)j0 * 4 + ch];
        u32x4 r1 = ybs[(size_t)j1 * 4 + ch];
        u32x4 r2 = ybs[(size_t)j2 * 4 + ch];
        u32x4 r3 = ybs[(size_t)j3 * 4 + ch];
        u32x4 r4 = ybs[(size_t)j4 * 4 + ch];
        u32x4 r5 = ybs[(size_t)j5 * 4 + ch];
        u32x4 r6 = ybs[(size_t)j6 * 4 + ch];
        acc8(r0, a);
        if (rem > 1) acc8(r1, a);
        if (rem > 2) acc8(r2, a);
        if (rem > 3) acc8(r3, a);
        if (rem > 4) acc8(r4, a);
        if (rem > 5) acc8(r5, a);
        if (rem > 6) acc8(r6, a);
    }

    u32x4 r;
    r.x = (unsigned)f2b(a[0] * di) | ((unsigned)f2b(a[1] * di) << 16);
    r.y = (unsigned)f2b(a[2] * di) | ((unsigned)f2b(a[3] * di) << 16);
    r.z = (unsigned)f2b(a[4] * di) | ((unsigned)f2b(a[5] * di) << 16);
    r.w = (unsigned)f2b(a[6] * di) | ((unsigned)f2b(a[7] * di) << 16);
    __builtin_nontemporal_store(r, &aggbf[(size_t)node * 32 + slice * 4 + ch]);
}

// fp32 fallback (only if ws too small for yb)
__global__ void k_agg_f32(const float4* __restrict__ x4, const int* __restrict__ fill,
                          const unsigned short* __restrict__ bucket,
                          ushort4* __restrict__ aggbf, int n) {
    int node = (blockIdx.x * blockDim.x + threadIdx.x) >> 6;
    int lane = threadIdx.x & 63;
    if (node >= n) return;

    int c = fill[node];
    float di = rsqrtf((float)(1 + c));
    if (c > CAP) c = CAP;

    float4 xi = x4[(size_t)node * 64 + lane];
    float a0 = di * xi.x, a1 = di * xi.y, a2 = di * xi.z, a3 = di * xi.w;

    const unsigned short* bk = bucket + (size_t)node * CAP;
    for (int k = 0; k < c; k++) {
        int j = bk[k];
        float dj = rsqrtf((float)(1 + fill[j]));
        float4 xj = x4[(size_t)j * 64 + lane];
        a0 += dj * xj.x; a1 += dj * xj.y; a2 += dj * xj.z; a3 += dj * xj.w;
    }
    ushort4 r;
    r.x = f2b(a0 * di); r.y = f2b(a1 * di);
    r.z = f2b(a2 * di); r.w = f2b(a3 * di);
    aggbf[(size_t)node * 64 + lane] = r;
}

// GEMM v3: register-resident weight-stationary (R3 win; keep).
// 32-col blocks (grid.y=8); wave = 16 rows x 32 cols; both matrices' weight
// fragments in 128 VGPR (read once from 32KB LDS stage); K-loop pure reg MFMA;
// all 8 A-loads issued up front; swapped mfma(w,a,acc) -> float4 nt stores.
__launch_bounds__(256, 2)
__global__ void k_gemm(const short* __restrict__ aggbf,
                       const short* __restrict__ wt1, const short* __restrict__ wt2,
                       const float* __restrict__ b1, const float* __restrict__ b2,
                       float* __restrict__ out, int n, int ntiles) {
    __shared__ u32x4 bs[2048];   // [mat][nn 0..31][p 0..31] XOR-swizzled, 32 KB

    int c0  = blockIdx.y * 32;
    int tid = threadIdx.x;

#pragma unroll
    for (int i = 0; i < 8; i++) {
        int l = tid + i * 256;                 // 0..2047
        int m = l >> 10, rem = l & 1023, nn = rem >> 5, p = rem & 31;
        const short* base = (m == 0) ? wt1 : wt2;
        const u32x4* sp = (const u32x4*)(base + (size_t)(c0 + nn) * DIM) + p;
        bs[(m << 10) + (nn << 5) + (p ^ nn)] = *sp;
    }
    __syncthreads();

    int lane = tid & 63;
    int wave = tid >> 6;
    int lrow = lane & 15;
    int quad = lane >> 4;

    // one-time: weight fragments -> registers (32 x bf16x8 = 128 VGPR)
    bf16x8 w1r[2][8], w2r[2][8];
#pragma unroll
    for (int ct = 0; ct < 2; ct++) {
        int nn = ct * 16 + lrow;
#pragma unroll
        for (int s = 0; s < 8; s++) {
            int p = (4 * s + quad) ^ nn;
            u32x4 u = bs[(nn << 5) + p];
            u32x4 v = bs[1024 + (nn << 5) + p];
            __builtin_memcpy(&w1r[ct][s], &u, 16);
            __builtin_memcpy(&w2r[ct][s], &v, 16);
        }
    }

    f32x4 bb1[2], bb2[2];
#pragma unroll
    for (int ct = 0; ct < 2; ct++) {
        bb1[ct] = *(const f32x4*)&b1[c0 + ct * 16 + quad * 4];
        bb2[ct] = *(const f32x4*)&b2[c0 + ct * 16 + quad * 4];
    }

    for (int t = blockIdx.x; t < ntiles; t += gridDim.x) {
        int row = t * 64 + wave * 16 + lrow;
        int r = (row < n) ? row : 0;
        const short* ap = aggbf + (size_t)r * DIM + quad * 8;

        // all 8 K-chunks of this row issued together: one latency exposure
        bf16x8 A[8];
#pragma unroll
        for (int s = 0; s < 8; s++) A[s] = *(const bf16x8*)(ap + s * 32);

        f32x4 acc1[2], acc2[2];
#pragma unroll
        for (int ct = 0; ct < 2; ct++) {
            acc1[ct] = (f32x4){0.f, 0.f, 0.f, 0.f};
            acc2[ct] = (f32x4){0.f, 0.f, 0.f, 0.f};
        }

#pragma unroll
        for (int s = 0; s < 8; s++) {
#pragma unroll
            for (int ct = 0; ct < 2; ct++) {
                acc1[ct] = __builtin_amdgcn_mfma_f32_16x16x32_bf16(w1r[ct][s], A[s], acc1[ct], 0, 0, 0);
                acc2[ct] = __builtin_amdgcn_mfma_f32_16x16x32_bf16(w2r[ct][s], A[s], acc2[ct], 0, 0, 0);
            }
        }

        if (row < n) {
#pragma unroll
            for (int ct = 0; ct < 2; ct++) {
                f32x4 v;
#pragma unroll
                for (int i = 0; i < 4; i++)
                    v[i] = fmaxf(acc1[ct][i] + bb1[ct][i], 0.f) + acc2[ct][i] + bb2[ct][i];
                f32x4* dstp = (f32x4*)&out[(size_t)row * DIM + c0 + ct * 16 + quad * 4];
                __builtin_nontemporal_store(v, dstp);
            }
        }
    }
}

extern "C" void kernel_launch(void* const* d_in, const int* in_sizes, int n_in,
                              void* d_out, int out_size, void* d_ws, size_t ws_size,
                              hipStream_t stream) {
    const float* x  = (const float*)d_in[0];
    const int*   ei = (const int*)d_in[1];    // [2, E] row-major, int32
    const float* W1 = (const float*)d_in[2];
    const float* b1 = (const float*)d_in[3];
    const float* W2 = (const float*)d_in[4];
    const float* b2 = (const float*)d_in[5];
    float* out = (float*)d_out;

    int n = in_sizes[0] / DIM;                // 50000
    int E = in_sizes[1] / 2;                  // 800000
    const int* src = ei;
    const int* dst = ei + E;

    char* ws = (char*)d_ws;
    int*            fill   = (int*)(ws + OFF_FILL);
    unsigned short* wt1    = (unsigned short*)(ws + OFF_WT1);
    unsigned short* wt2    = (unsigned short*)(ws + OFF_WT2);
    unsigned short* bucket = (unsigned short*)(ws + OFF_BUCKET);
    char*           aggp   = ws + OFF_AGG;
    u32x4*          yb     = (u32x4*)(ws + OFF_YB);

    (void)hipMemsetAsync(fill, 0, n * sizeof(int), stream);

    k_fill<<<(E + 255) / 256, 256, 0, stream>>>(src, dst, fill, bucket, E);

    bool use_bf = (ws_size >= NEED_BF);      // constant across calls -> graph-safe
    if (use_bf) {
        int n8 = n * (DIM / 8);              // 1.6M 8-elem groups
        int nybBlocks = (n8 + 255) / 256;    // 6250
        k_prep<<<nybBlocks + 256, 256, 0, stream>>>(x, fill, yb, W1, W2, wt1, wt2,
                                                    nybBlocks, n8);
        // 8 slices x 64 nodes/block; slice = blockIdx&7 -> XCD-pinned
        int aggBlocks = ((n + 63) / 64) * 8;  // 782*8 = 6256
        k_agg_bf<<<aggBlocks, 256, 0, stream>>>(yb, fill, bucket, (u32x4*)aggp, n);
    } else {
        k_prep<<<256, 256, 0, stream>>>(x, fill, yb, W1, W2, wt1, wt2, 0, 0);
        int aggBlocks = (n * 64 + 255) / 256;
        k_agg_f32<<<aggBlocks, 256, 0, stream>>>((const float4*)x, fill, bucket,
                                                 (ushort4*)aggp, n);
    }

    int ntiles = (n + 63) / 64;              // 782 row-tiles of 64
    dim3 ggrid(GEMM_BX, DIM / 32);           // 64 x 8 = 512 blocks (2/CU resident)
    k_gemm<<<ggrid, 256, 0, stream>>>((const short*)aggp, (const short*)wt1,
                                      (const short*)wt2, b1, b2, out, n, ntiles);
}